// Round 5
// baseline (737.123 us; speedup 1.0000x reference)
//
#include <hip/hip_runtime.h>
#include <cmath>

#define NV   262144
#define NE   786432
#define CIMG 256
#define HID  128
#define NPIX 4096
#define DIN  131
#define KB   160    // bf16 feats padded K (131 -> 160, zeros)
#define KBP  168    // LDS row stride (bank-conflict pad)
#define NBKT 256    // coarse buckets for CSR build (1024 vertices each)

typedef short bf8v __attribute__((ext_vector_type(8)));
typedef float f4v  __attribute__((ext_vector_type(4)));
typedef unsigned short u16x8 __attribute__((ext_vector_type(8)));
typedef unsigned short u16x4 __attribute__((ext_vector_type(4)));

__device__ __forceinline__ unsigned short f2bf(float v) {
    unsigned int u = __float_as_uint(v);
    u = u + 0x7fffu + ((u >> 16) & 1u);   // RNE
    return (unsigned short)(u >> 16);
}
__device__ __forceinline__ float bf2f(unsigned short b) {
    return __uint_as_float(((unsigned int)b) << 16);
}

// P[p][j] = sum_c img[c][p] * bw[c][j]; 8 pixels/block, 512 blocks.
__global__ __launch_bounds__(256) void k_project(const float* __restrict__ img,
                                                 const float* __restrict__ bw,
                                                 float* __restrict__ P) {
    int j  = threadIdx.x & 127;
    int pr = threadIdx.x >> 7;
    int pbase = blockIdx.x * 8 + pr * 4;
    f4v a = {0.f, 0.f, 0.f, 0.f};
#pragma unroll 4
    for (int c = 0; c < CIMG; ++c) {
        float bwv = bw[c * HID + j];
        f4v iv = __builtin_nontemporal_load((const f4v*)(img + (size_t)c * NPIX + pbase));
        a[0] += iv[0] * bwv; a[1] += iv[1] * bwv;
        a[2] += iv[2] * bwv; a[3] += iv[3] * bwv;
    }
    P[(size_t)(pbase + 0) * HID + j] = a[0];
    P[(size_t)(pbase + 1) * HID + j] = a[1];
    P[(size_t)(pbase + 2) * HID + j] = a[2];
    P[(size_t)(pbase + 3) * HID + j] = a[3];
}

// feats[v][0..127] = relu(bilerp + bb) bf16; [128..130]=verts; [131..159]=0
// 16 lanes/vertex, 8 channels/lane: float4 loads (16B/lane), u16x8 stores.
__global__ __launch_bounds__(256) void k_sample(const float* __restrict__ P,
                                                const float* __restrict__ verts,
                                                const float* __restrict__ bb,
                                                unsigned short* __restrict__ feats) {
    int cq = threadIdx.x & 15;                  // 8 channels: 8*cq .. 8*cq+7
    int v  = blockIdx.x * 16 + (threadIdx.x >> 4);
    float vx = verts[(size_t)v * 3 + 0];
    float vy = verts[(size_t)v * 3 + 1];
    float px = (vx + 1.f) * 31.5f;
    float py = (vy + 1.f) * 31.5f;
    float x0f = floorf(px), y0f = floorf(py);
    float wx = px - x0f,   wy = py - y0f;
    int x0 = (int)x0f, y0 = (int)y0f;
    int x0i = min(max(x0, 0), 63);
    int x1i = min(x0i + 1, 63);
    int y0i = min(max(y0, 0), 63);
    int y1i = min(y0i + 1, 63);
    float w00 = (1.f - wx) * (1.f - wy);
    float w01 = wx * (1.f - wy);
    float w10 = (1.f - wx) * wy;
    float w11 = wx * wy;
    const float* p00 = P + (size_t)(y0i * 64 + x0i) * HID + 8 * cq;
    const float* p01 = P + (size_t)(y0i * 64 + x1i) * HID + 8 * cq;
    const float* p10 = P + (size_t)(y1i * 64 + x0i) * HID + 8 * cq;
    const float* p11 = P + (size_t)(y1i * 64 + x1i) * HID + 8 * cq;
    float4 a00 = *(const float4*)(p00), b00 = *(const float4*)(p00 + 4);
    float4 a01 = *(const float4*)(p01), b01 = *(const float4*)(p01 + 4);
    float4 a10 = *(const float4*)(p10), b10 = *(const float4*)(p10 + 4);
    float4 a11 = *(const float4*)(p11), b11 = *(const float4*)(p11 + 4);
    float4 bba = *(const float4*)(bb + 8 * cq);
    float4 bbb = *(const float4*)(bb + 8 * cq + 4);
    float r[8];
    r[0] = a00.x * w00 + a01.x * w01 + a10.x * w10 + a11.x * w11 + bba.x;
    r[1] = a00.y * w00 + a01.y * w01 + a10.y * w10 + a11.y * w11 + bba.y;
    r[2] = a00.z * w00 + a01.z * w01 + a10.z * w10 + a11.z * w11 + bba.z;
    r[3] = a00.w * w00 + a01.w * w01 + a10.w * w10 + a11.w * w11 + bba.w;
    r[4] = b00.x * w00 + b01.x * w01 + b10.x * w10 + b11.x * w11 + bbb.x;
    r[5] = b00.y * w00 + b01.y * w01 + b10.y * w10 + b11.y * w11 + bbb.y;
    r[6] = b00.z * w00 + b01.z * w01 + b10.z * w10 + b11.z * w11 + bbb.z;
    r[7] = b00.w * w00 + b01.w * w01 + b10.w * w10 + b11.w * w11 + bbb.w;
    u16x8 o;
#pragma unroll
    for (int i = 0; i < 8; ++i) o[i] = f2bf(fmaxf(r[i], 0.f));
    *(u16x8*)(feats + (size_t)v * KB + 8 * cq) = o;
    if (cq < 4) {
        u16x8 t;
#pragma unroll
        for (int i = 0; i < 8; ++i) {
            int k = 8 * cq + i;                 // 0..31 -> feats col 128..159
            float val = (k < 3) ? verts[(size_t)v * 3 + k] : 0.f;
            t[i] = f2bf(val);
        }
        *(u16x8*)(feats + (size_t)v * KB + 128 + 8 * cq) = t;
    }
}

// Wt[m][n][k] bf16, m = layer*2+g, transposed from W[k][n], zero-padded k>=131
__global__ __launch_bounds__(256) void k_prepw(const float* __restrict__ w0,
                                               const float* __restrict__ w1,
                                               unsigned short* __restrict__ Wt) {
    int idx = blockIdx.x * 256 + threadIdx.x;
    if (idx >= 6 * 128) return;
    int m = idx >> 7;
    int n = idx & 127;
    int layer = m >> 1, g = m & 1;
    const float* W = (g ? w1 : w0) + (size_t)layer * DIN * HID;
    unsigned short* dst = Wt + (size_t)(m * 128 + n) * KB;
    for (int k = 0; k < KB; ++k) {
        float v = (k < DIN) ? W[(size_t)k * HID + n] : 0.f;
        dst[k] = f2bf(v);
    }
}

// Fused MFMA GEMM: y = feats@W0+b0 (bf16), z = feats@W1+b1 (bf16).
// Operands SWAPPED (compute C^T): lane's 4 acc regs = 4 consecutive channels of
// one vertex -> pack with f2bf into u16x4, single 8B store per tile.
__global__ __launch_bounds__(256, 2) void k_gemm2(const unsigned short* __restrict__ feats,
                                                  const unsigned short* __restrict__ Wt0,
                                                  const unsigned short* __restrict__ Wt1,
                                                  const float* __restrict__ bias0,
                                                  const float* __restrict__ bias1,
                                                  unsigned short* __restrict__ y,
                                                  unsigned short* __restrict__ z) {
    __shared__ unsigned short As[64 * KBP];     // 21 KB
    int lane = threadIdx.x & 63;
    int wave = threadIdx.x >> 6;     // column quarter: cols 32*wave..+31
    int l15  = lane & 15;
    int quad = lane >> 4;

    bf8v bfrag[2][2][5];
#pragma unroll
    for (int g = 0; g < 2; ++g) {
        const unsigned short* Wg = g ? Wt1 : Wt0;
#pragma unroll
        for (int ct = 0; ct < 2; ++ct) {
            int n = wave * 32 + ct * 16 + l15;
#pragma unroll
            for (int ks = 0; ks < 5; ++ks)
                bfrag[g][ct][ks] = *(const bf8v*)(Wg + (size_t)n * KB + ks * 32 + quad * 8);
        }
    }
    // bias: acc reg r maps to channel wave*32 + ct*16 + quad*4 + r
    f4v bv[2][2];
#pragma unroll
    for (int g = 0; g < 2; ++g)
#pragma unroll
        for (int ct = 0; ct < 2; ++ct) {
            float4 b4 = *(const float4*)((g ? bias1 : bias0) + wave * 32 + ct * 16 + quad * 4);
            f4v t = {b4.x, b4.y, b4.z, b4.w};
            bv[g][ct] = t;
        }

    int vb0 = blockIdx.x * 256;

    // staging coords: 64 rows x 20 groups of 8 elems; 1280 groups / 256 thr = 5 each
    int srow[5], scol[5];
#pragma unroll
    for (int j = 0; j < 5; ++j) {
        int g = threadIdx.x + 256 * j;
        srow[j] = g / 20;
        scol[j] = (g % 20) * 8;
    }

    u16x8 st[5];
#pragma unroll
    for (int j = 0; j < 5; ++j)
        st[j] = __builtin_nontemporal_load(
            (const u16x8*)(feats + (size_t)(vb0 + srow[j]) * KB + scol[j]));
#pragma unroll
    for (int j = 0; j < 5; ++j)
        *(u16x8*)(&As[srow[j] * KBP + scol[j]]) = st[j];
    __syncthreads();

    for (int ch = 0; ch < 4; ++ch) {
        if (ch < 3) {
#pragma unroll
            for (int j = 0; j < 5; ++j)
                st[j] = __builtin_nontemporal_load(
                    (const u16x8*)(feats + (size_t)(vb0 + (ch + 1) * 64 + srow[j]) * KB + scol[j]));
        }
        f4v acc[4][2][2];
#pragma unroll
        for (int m = 0; m < 4; ++m)
#pragma unroll
            for (int g = 0; g < 2; ++g)
#pragma unroll
                for (int ct = 0; ct < 2; ++ct)
                    acc[m][g][ct] = bv[g][ct];
#pragma unroll
        for (int ks = 0; ks < 5; ++ks) {
            bf8v af[4];
#pragma unroll
            for (int m = 0; m < 4; ++m)
                af[m] = *(const bf8v*)(&As[(m * 16 + l15) * KBP + ks * 32 + quad * 8]);
#pragma unroll
            for (int m = 0; m < 4; ++m)
#pragma unroll
                for (int g = 0; g < 2; ++g)
#pragma unroll
                    for (int ct = 0; ct < 2; ++ct)
                        acc[m][g][ct] = __builtin_amdgcn_mfma_f32_16x16x32_bf16(
                            bfrag[g][ct][ks], af[m], acc[m][g][ct], 0, 0, 0);
        }
        int vbase = vb0 + ch * 64;
#pragma unroll
        for (int m = 0; m < 4; ++m) {
            int vtx = vbase + m * 16 + l15;
#pragma unroll
            for (int g = 0; g < 2; ++g) {
                unsigned short* dst = g ? z : y;
#pragma unroll
                for (int ct = 0; ct < 2; ++ct) {
                    int c0 = wave * 32 + ct * 16 + quad * 4;
                    u16x4 pv;
#pragma unroll
                    for (int r = 0; r < 4; ++r) pv[r] = f2bf(acc[m][g][ct][r]);
                    *(u16x4*)(&dst[(size_t)vtx * HID + c0]) = pv;
                }
            }
        }
        __syncthreads();
        if (ch < 3) {
#pragma unroll
            for (int j = 0; j < 5; ++j)
                *(u16x8*)(&As[srow[j] * KBP + scol[j]]) = st[j];
            __syncthreads();
        }
    }
}

// ---- CSR build via 2-level bucket sort ----
__global__ __launch_bounds__(256) void k_hist(const int4* __restrict__ edges4,
                                              int* __restrict__ gcount) {
    __shared__ int hist[NBKT];
    if (threadIdx.x < NBKT) hist[threadIdx.x] = 0;
    __syncthreads();
#pragma unroll
    for (int i = 0; i < 4; ++i) {
        int4 e = edges4[(size_t)blockIdx.x * 1024 + i * 256 + threadIdx.x];
        atomicAdd(&hist[e.x >> 10], 1);
        atomicAdd(&hist[e.y >> 10], 1);
        atomicAdd(&hist[e.z >> 10], 1);
        atomicAdd(&hist[e.w >> 10], 1);
    }
    __syncthreads();
    if (threadIdx.x < NBKT) atomicAdd(&gcount[threadIdx.x], hist[threadIdx.x]);
}

__global__ __launch_bounds__(256) void k_scan256(const int* __restrict__ gcount,
                                                 int* __restrict__ bbase,
                                                 int* __restrict__ bcur,
                                                 int* __restrict__ rowstart) {
    __shared__ int s[NBKT];
    int t = threadIdx.x;
    int c = gcount[t];
    s[t] = c;
    __syncthreads();
    for (int off = 1; off < NBKT; off <<= 1) {
        int v = (t >= off) ? s[t - off] : 0;
        __syncthreads();
        s[t] += v;
        __syncthreads();
    }
    bbase[t] = s[t] - c;
    bcur[t]  = s[t] - c;
    if (t == NBKT - 1) {
        bbase[NBKT] = s[t];
        rowstart[NV] = s[t];
    }
}

__global__ __launch_bounds__(256) void k_binA(const int4* __restrict__ edges4,
                                              int* __restrict__ bcur,
                                              unsigned int* __restrict__ items) {
    __shared__ int hist[NBKT];
    __shared__ int loff[NBKT];
    __shared__ int gbase[NBKT];
    __shared__ int sscan[256];
    __shared__ unsigned int staged[4096];
    __shared__ unsigned char staged_b[4096];

    if (threadIdx.x < NBKT) hist[threadIdx.x] = 0;
    __syncthreads();

    int vv[16], uu[16], rk[16];
#pragma unroll
    for (int i = 0; i < 4; ++i) {
        int4 e = edges4[(size_t)blockIdx.x * 1024 + i * 256 + threadIdx.x];
        vv[4*i+0] = e.x; uu[4*i+0] = e.y;
        vv[4*i+1] = e.y; uu[4*i+1] = e.x;
        vv[4*i+2] = e.z; uu[4*i+2] = e.w;
        vv[4*i+3] = e.w; uu[4*i+3] = e.z;
    }
#pragma unroll
    for (int i = 0; i < 16; ++i) rk[i] = atomicAdd(&hist[vv[i] >> 10], 1);
    __syncthreads();
    {
        int t = threadIdx.x;
        int c = hist[t];
        sscan[t] = c;
        __syncthreads();
        for (int off = 1; off < 256; off <<= 1) {
            int x = (t >= off) ? sscan[t - off] : 0;
            __syncthreads();
            sscan[t] += x;
            __syncthreads();
        }
        loff[t] = sscan[t] - c;
    }
    __syncthreads();
#pragma unroll
    for (int i = 0; i < 16; ++i) {
        int b = vv[i] >> 10;
        int pos = loff[b] + rk[i];
        staged[pos] = ((unsigned int)(vv[i] & 1023) << 18) | (unsigned int)uu[i];
        staged_b[pos] = (unsigned char)b;
    }
    __syncthreads();
    if (threadIdx.x < NBKT)
        gbase[threadIdx.x] = atomicAdd(&bcur[threadIdx.x], hist[threadIdx.x]);
    __syncthreads();
#pragma unroll
    for (int i = 0; i < 16; ++i) {
        int s = i * 256 + threadIdx.x;
        int b = staged_b[s];
        items[(size_t)gbase[b] + (s - loff[b])] = staged[s];
    }
}

__global__ __launch_bounds__(256) void k_binB(const unsigned int* __restrict__ items,
                                              const int* __restrict__ bbase,
                                              int* __restrict__ rowstart,
                                              int* __restrict__ adj) {
    __shared__ int cnt[1024];
    __shared__ int sscan[256];
    int b = blockIdx.x;
    int base = bbase[b];
    int size = bbase[b + 1] - base;
#pragma unroll
    for (int i = 0; i < 4; ++i) cnt[i * 256 + threadIdx.x] = 0;
    __syncthreads();
    for (int i = threadIdx.x; i < size; i += 256) {
        unsigned int it = items[(size_t)base + i];
        atomicAdd(&cnt[(it >> 18) & 1023], 1);
    }
    __syncthreads();
    {
        int j = threadIdx.x;
        int c[4], t = 0;
#pragma unroll
        for (int i = 0; i < 4; ++i) { c[i] = cnt[4 * j + i]; t += c[i]; }
        sscan[j] = t;
        __syncthreads();
        for (int off = 1; off < 256; off <<= 1) {
            int x = (j >= off) ? sscan[j - off] : 0;
            __syncthreads();
            sscan[j] += x;
            __syncthreads();
        }
        int pre = sscan[j] - t;
#pragma unroll
        for (int i = 0; i < 4; ++i) {
            cnt[4 * j + i] = pre;
            rowstart[b * 1024 + 4 * j + i] = base + pre;
            pre += c[i];
        }
    }
    __syncthreads();
    for (int i = threadIdx.x; i < size; i += 256) {
        unsigned int it = items[(size_t)base + i];
        int lv = (it >> 18) & 1023;
        int rel = atomicAdd(&cnt[lv], 1);
        // store neighbor pre-scaled to element offset into a 128-ch row
        adj[base + rel] = (int)((it & 0x3FFFFu) << 7);
    }
}

// relu(y[v] + sum_{u in N(v)} z[u]); 16 lanes/vertex.
// Streaming accesses (ybf read, acc/out writes) are NON-TEMPORAL so the
// randomly-gathered zbf (64 MB) stays L3-resident.
template <bool LAST>
__global__ __launch_bounds__(256) void k_gather(const int* __restrict__ rowstart,
                                                const int* __restrict__ adj,
                                                const unsigned short* __restrict__ zbf,
                                                const unsigned short* __restrict__ ybf,
                                                unsigned short* __restrict__ featdst,
                                                float* __restrict__ accdst,
                                                const float* __restrict__ verts,
                                                const float* __restrict__ ow,
                                                const float* __restrict__ ob,
                                                float* __restrict__ outp) {
    __shared__ float owl[DIN * 3];
    if (LAST) {
        for (int idx = threadIdx.x; idx < DIN * 3; idx += 256) owl[idx] = ow[idx];
        __syncthreads();
    }
    int cq = threadIdx.x & 15;
    int co = 8 * cq;
    int v  = blockIdx.x * 16 + (threadIdx.x >> 4);
    int start = rowstart[v], end = rowstart[v + 1];
    u16x8 yy = __builtin_nontemporal_load((const u16x8*)(ybf + ((unsigned)v << 7) + co));
    float a0[8], a1[8];
#pragma unroll
    for (int i = 0; i < 8; ++i) { a0[i] = bf2f(yy[i]); a1[i] = 0.f; }
    int n = start;
    for (; n + 4 <= end; n += 4) {
        int u0 = adj[n + 0], u1 = adj[n + 1];
        int u2 = adj[n + 2], u3 = adj[n + 3];
        u16x8 z0 = *(const u16x8*)(zbf + (unsigned)(u0 + co));
        u16x8 z1 = *(const u16x8*)(zbf + (unsigned)(u1 + co));
        u16x8 z2 = *(const u16x8*)(zbf + (unsigned)(u2 + co));
        u16x8 z3 = *(const u16x8*)(zbf + (unsigned)(u3 + co));
#pragma unroll
        for (int i = 0; i < 8; ++i) a0[i] += bf2f(z0[i]) + bf2f(z1[i]);
#pragma unroll
        for (int i = 0; i < 8; ++i) a1[i] += bf2f(z2[i]) + bf2f(z3[i]);
    }
    if (n + 2 <= end) {
        int u0 = adj[n + 0], u1 = adj[n + 1];
        u16x8 z0 = *(const u16x8*)(zbf + (unsigned)(u0 + co));
        u16x8 z1 = *(const u16x8*)(zbf + (unsigned)(u1 + co));
#pragma unroll
        for (int i = 0; i < 8; ++i) a0[i] += bf2f(z0[i]) + bf2f(z1[i]);
        n += 2;
    }
    if (n < end) {
        int u = adj[n];
        u16x8 zz = *(const u16x8*)(zbf + (unsigned)(u + co));
#pragma unroll
        for (int i = 0; i < 8; ++i) a1[i] += bf2f(zz[i]);
    }
    float a[8];
#pragma unroll
    for (int i = 0; i < 8; ++i) a[i] = fmaxf(a0[i] + a1[i], 0.f);
    if (LAST) {
        f4v lo = {a[0], a[1], a[2], a[3]};
        f4v hi = {a[4], a[5], a[6], a[7]};
        float* dst = accdst + ((size_t)v << 7) + co;
        __builtin_nontemporal_store(lo, (f4v*)(dst + 0));
        __builtin_nontemporal_store(hi, (f4v*)(dst + 4));
        float d0 = 0.f, d1 = 0.f, d2 = 0.f;
#pragma unroll
        for (int i = 0; i < 8; ++i) {
            int k = co + i;
            d0 += a[i] * owl[k * 3 + 0];
            d1 += a[i] * owl[k * 3 + 1];
            d2 += a[i] * owl[k * 3 + 2];
        }
#pragma unroll
        for (int off = 8; off > 0; off >>= 1) {
            d0 += __shfl_down(d0, off, 16);
            d1 += __shfl_down(d1, off, 16);
            d2 += __shfl_down(d2, off, 16);
        }
        if (cq == 0) {
            float vx = verts[(size_t)v * 3 + 0];
            float vy = verts[(size_t)v * 3 + 1];
            float vz = verts[(size_t)v * 3 + 2];
            d0 += vx * owl[128*3+0] + vy * owl[129*3+0] + vz * owl[130*3+0] + ob[0];
            d1 += vx * owl[128*3+1] + vy * owl[129*3+1] + vz * owl[130*3+1] + ob[1];
            d2 += vx * owl[128*3+2] + vy * owl[129*3+2] + vz * owl[130*3+2] + ob[2];
            outp[(size_t)v * 3 + 0] = vx + tanhf(d0);
            outp[(size_t)v * 3 + 1] = vy + tanhf(d1);
            outp[(size_t)v * 3 + 2] = vz + tanhf(d2);
        }
    } else {
        u16x8 o;
#pragma unroll
        for (int i = 0; i < 8; ++i) o[i] = f2bf(a[i]);
        *(u16x8*)(featdst + (size_t)v * KB + co) = o;
    }
}

extern "C" void kernel_launch(void* const* d_in, const int* in_sizes, int n_in,
                              void* d_out, int out_size, void* d_ws, size_t ws_size,
                              hipStream_t stream) {
    const float* x     = (const float*)d_in[0];
    const float* verts = (const float*)d_in[1];
    const int*   edges = (const int*)d_in[2];
    const float* bw    = (const float*)d_in[3];
    const float* bb    = (const float*)d_in[4];
    const float* w0    = (const float*)d_in[5];
    const float* b0    = (const float*)d_in[6];
    const float* w1    = (const float*)d_in[7];
    const float* b1    = (const float*)d_in[8];
    const float* ow    = (const float*)d_in[9];
    const float* ob    = (const float*)d_in[10];
    float* out = (float*)d_out;

    char* w = (char*)d_ws;
    float* P              = (float*)w;          w += (size_t)NPIX * HID * 4;
    unsigned short* feats = (unsigned short*)w; w += (size_t)NV * KB * 2;
    unsigned short* zbf   = (unsigned short*)w; w += (size_t)NV * HID * 2;
    unsigned short* ybf   = (unsigned short*)w; w += (size_t)NV * HID * 2;
    unsigned short* Wt    = (unsigned short*)w; w += (size_t)6 * 128 * KB * 2;
    int* adj              = (int*)w;            w += (size_t)2 * NE * 4;
    unsigned int* items   = (unsigned int*)w;   w += (size_t)2 * NE * 4;
    int* rowstart         = (int*)w;            w += (size_t)(NV + 1) * 4;
    int* gcount           = (int*)w;            w += 512 * 4;
    int* bbase            = (int*)w;            w += 512 * 4;
    int* bcur             = (int*)w;            w += 512 * 4;
    float* acc            = out + (size_t)3 * NV;

    hipMemsetAsync(gcount, 0, NBKT * 4, stream);
    k_hist<<<NE / 2048, 256, 0, stream>>>((const int4*)edges, gcount);
    k_scan256<<<1, 256, 0, stream>>>(gcount, bbase, bcur, rowstart);
    k_binA<<<NE / 2048, 256, 0, stream>>>((const int4*)edges, bcur, items);
    k_binB<<<NBKT, 256, 0, stream>>>(items, bbase, rowstart, adj);

    k_prepw<<<3, 256, 0, stream>>>(w0, w1, Wt);
    k_project<<<NPIX / 8, 256, 0, stream>>>(x, bw, P);
    k_sample<<<NV / 16, 256, 0, stream>>>(P, verts, bb, feats);

    for (int i = 0; i < 3; ++i) {
        const unsigned short* Wt0 = Wt + (size_t)(2 * i + 0) * 128 * KB;
        const unsigned short* Wt1 = Wt + (size_t)(2 * i + 1) * 128 * KB;
        k_gemm2<<<NV / 256, 256, 0, stream>>>(feats, Wt0, Wt1,
                                              b0 + (size_t)i * HID, b1 + (size_t)i * HID,
                                              ybf, zbf);
        if (i < 2) k_gather<false><<<NV / 16, 256, 0, stream>>>(rowstart, adj, zbf, ybf,
                                                                feats, nullptr, verts,
                                                                nullptr, nullptr, nullptr);
        else       k_gather<true ><<<NV / 16, 256, 0, stream>>>(rowstart, adj, zbf, ybf,
                                                                nullptr, acc, verts,
                                                                ow, ob, out);
    }
}

// Round 7
// 661.617 us; speedup vs baseline: 1.1141x; 1.1141x over previous
//
#include <hip/hip_runtime.h>
#include <cmath>

#define NV   262144
#define NE   786432
#define CIMG 256
#define HID  128
#define NPIX 4096
#define DIN  131
#define KB   128    // bf16 feats K (image features only; verts handled in epilogue)
#define KBP  136    // LDS row stride (bank-conflict pad)
#define NBKT 256    // coarse buckets for CSR build (1024 vertices each)

typedef short bf8v __attribute__((ext_vector_type(8)));
typedef float f4v  __attribute__((ext_vector_type(4)));
typedef unsigned short u16x8 __attribute__((ext_vector_type(8)));
typedef unsigned short u16x4 __attribute__((ext_vector_type(4)));

__device__ __forceinline__ unsigned short f2bf(float v) {
    unsigned int u = __float_as_uint(v);
    u = u + 0x7fffu + ((u >> 16) & 1u);   // RNE
    return (unsigned short)(u >> 16);
}
__device__ __forceinline__ float bf2f(unsigned short b) {
    return __uint_as_float(((unsigned int)b) << 16);
}

// P[p][j] = sum_c img[c][p] * bw[c][j]; 8 pixels/block, 512 blocks.
__global__ __launch_bounds__(256) void k_project(const float* __restrict__ img,
                                                 const float* __restrict__ bw,
                                                 float* __restrict__ P) {
    int j  = threadIdx.x & 127;
    int pr = threadIdx.x >> 7;
    int pbase = blockIdx.x * 8 + pr * 4;
    float4 a = {0.f, 0.f, 0.f, 0.f};
#pragma unroll 4
    for (int c = 0; c < CIMG; ++c) {
        float bwv = bw[c * HID + j];
        float4 iv = *(const float4*)(img + (size_t)c * NPIX + pbase);
        a.x += iv.x * bwv; a.y += iv.y * bwv;
        a.z += iv.z * bwv; a.w += iv.w * bwv;
    }
    P[(size_t)(pbase + 0) * HID + j] = a.x;
    P[(size_t)(pbase + 1) * HID + j] = a.y;
    P[(size_t)(pbase + 2) * HID + j] = a.z;
    P[(size_t)(pbase + 3) * HID + j] = a.w;
}

// feats[v][0..127] = relu(bilerp + bb) bf16 (exactly 128 ch; no pad).
// 16 lanes/vertex, 8 channels/lane: float4 loads (16B/lane), u16x8 stores.
__global__ __launch_bounds__(256) void k_sample(const float* __restrict__ P,
                                                const float* __restrict__ verts,
                                                const float* __restrict__ bb,
                                                unsigned short* __restrict__ feats) {
    int cq = threadIdx.x & 15;                  // 8 channels: 8*cq .. 8*cq+7
    int v  = blockIdx.x * 16 + (threadIdx.x >> 4);
    float vx = verts[(size_t)v * 3 + 0];
    float vy = verts[(size_t)v * 3 + 1];
    float px = (vx + 1.f) * 31.5f;
    float py = (vy + 1.f) * 31.5f;
    float x0f = floorf(px), y0f = floorf(py);
    float wx = px - x0f,   wy = py - y0f;
    int x0 = (int)x0f, y0 = (int)y0f;
    int x0i = min(max(x0, 0), 63);
    int x1i = min(x0i + 1, 63);
    int y0i = min(max(y0, 0), 63);
    int y1i = min(y0i + 1, 63);
    float w00 = (1.f - wx) * (1.f - wy);
    float w01 = wx * (1.f - wy);
    float w10 = (1.f - wx) * wy;
    float w11 = wx * wy;
    const float* p00 = P + (size_t)(y0i * 64 + x0i) * HID + 8 * cq;
    const float* p01 = P + (size_t)(y0i * 64 + x1i) * HID + 8 * cq;
    const float* p10 = P + (size_t)(y1i * 64 + x0i) * HID + 8 * cq;
    const float* p11 = P + (size_t)(y1i * 64 + x1i) * HID + 8 * cq;
    float4 a00 = *(const float4*)(p00), b00 = *(const float4*)(p00 + 4);
    float4 a01 = *(const float4*)(p01), b01 = *(const float4*)(p01 + 4);
    float4 a10 = *(const float4*)(p10), b10 = *(const float4*)(p10 + 4);
    float4 a11 = *(const float4*)(p11), b11 = *(const float4*)(p11 + 4);
    float4 bba = *(const float4*)(bb + 8 * cq);
    float4 bbb = *(const float4*)(bb + 8 * cq + 4);
    float r[8];
    r[0] = a00.x * w00 + a01.x * w01 + a10.x * w10 + a11.x * w11 + bba.x;
    r[1] = a00.y * w00 + a01.y * w01 + a10.y * w10 + a11.y * w11 + bba.y;
    r[2] = a00.z * w00 + a01.z * w01 + a10.z * w10 + a11.z * w11 + bba.z;
    r[3] = a00.w * w00 + a01.w * w01 + a10.w * w10 + a11.w * w11 + bba.w;
    r[4] = b00.x * w00 + b01.x * w01 + b10.x * w10 + b11.x * w11 + bbb.x;
    r[5] = b00.y * w00 + b01.y * w01 + b10.y * w10 + b11.y * w11 + bbb.y;
    r[6] = b00.z * w00 + b01.z * w01 + b10.z * w10 + b11.z * w11 + bbb.z;
    r[7] = b00.w * w00 + b01.w * w01 + b10.w * w10 + b11.w * w11 + bbb.w;
    u16x8 o;
#pragma unroll
    for (int i = 0; i < 8; ++i) o[i] = f2bf(fmaxf(r[i], 0.f));
    *(u16x8*)(feats + ((size_t)v << 7) + 8 * cq) = o;
}

// Wt[m][n][k] bf16, m = layer*2+g, transposed from W[k][n], k<128 only.
__global__ __launch_bounds__(256) void k_prepw(const float* __restrict__ w0,
                                               const float* __restrict__ w1,
                                               unsigned short* __restrict__ Wt) {
    int idx = blockIdx.x * 256 + threadIdx.x;
    if (idx >= 6 * 128) return;
    int m = idx >> 7;
    int n = idx & 127;
    int layer = m >> 1, g = m & 1;
    const float* W = (g ? w1 : w0) + (size_t)layer * DIN * HID;
    unsigned short* dst = Wt + (size_t)(m * 128 + n) * KB;
    for (int k = 0; k < KB; ++k)
        dst[k] = f2bf(W[(size_t)k * HID + n]);
}

// Fused MFMA GEMM (K=128): y = feats@W0[:128]+b0, z = feats@W1[:128]+b1,
// verts @ W[128:131] added as register epilogue (weights rows in LDS as f32).
// Operands SWAPPED (compute C^T): lane's 4 acc regs = 4 consecutive channels of
// one vertex -> pack with f2bf into u16x4, single 8B store per tile.
__global__ __launch_bounds__(256, 2) void k_gemm2(const unsigned short* __restrict__ feats,
                                                  const unsigned short* __restrict__ Wt0,
                                                  const unsigned short* __restrict__ Wt1,
                                                  const float* __restrict__ wv0,
                                                  const float* __restrict__ wv1,
                                                  const float* __restrict__ bias0,
                                                  const float* __restrict__ bias1,
                                                  const float* __restrict__ verts,
                                                  unsigned short* __restrict__ y,
                                                  unsigned short* __restrict__ z) {
    __shared__ unsigned short As[64 * KBP];     // 17 KB
    __shared__ float wvf[2 * 3 * 128];          // 3 KB: W rows 128..130, both gemms
    __shared__ float vlds[256 * 3];             // 3 KB: verts tile
    int lane = threadIdx.x & 63;
    int wave = threadIdx.x >> 6;     // column quarter: cols 32*wave..+31
    int l15  = lane & 15;
    int quad = lane >> 4;

    bf8v bfrag[2][2][4];
#pragma unroll
    for (int g = 0; g < 2; ++g) {
        const unsigned short* Wg = g ? Wt1 : Wt0;
#pragma unroll
        for (int ct = 0; ct < 2; ++ct) {
            int n = wave * 32 + ct * 16 + l15;
#pragma unroll
            for (int ks = 0; ks < 4; ++ks)
                bfrag[g][ct][ks] = *(const bf8v*)(Wg + (size_t)n * KB + ks * 32 + quad * 8);
        }
    }
    // bias: acc reg r maps to channel wave*32 + ct*16 + quad*4 + r
    f4v bv[2][2];
#pragma unroll
    for (int g = 0; g < 2; ++g)
#pragma unroll
        for (int ct = 0; ct < 2; ++ct) {
            float4 b4 = *(const float4*)((g ? bias1 : bias0) + wave * 32 + ct * 16 + quad * 4);
            f4v t = {b4.x, b4.y, b4.z, b4.w};
            bv[g][ct] = t;
        }

    int vb0 = blockIdx.x * 256;

    // staging coords: 64 rows x 16 groups of 8 elems; 1024 groups / 256 thr = 4 each
    int srow[4], scol[4];
#pragma unroll
    for (int j = 0; j < 4; ++j) {
        int g = threadIdx.x + 256 * j;
        srow[j] = g >> 4;
        scol[j] = (g & 15) * 8;
    }

    u16x8 st[4];
#pragma unroll
    for (int j = 0; j < 4; ++j)
        st[j] = *(const u16x8*)(feats + ((size_t)(vb0 + srow[j]) << 7) + scol[j]);
#pragma unroll
    for (int j = 0; j < 4; ++j)
        *(u16x8*)(&As[srow[j] * KBP + scol[j]]) = st[j];
    // weight rows 128..130 (f32) and the 256-vertex coord tile
    for (int i = threadIdx.x; i < 768; i += 256)
        wvf[i] = (i < 384) ? wv0[i] : wv1[i - 384];
    for (int i = threadIdx.x; i < 768; i += 256)
        vlds[i] = verts[(size_t)vb0 * 3 + i];
    __syncthreads();

    // hoist verts-weight values for this lane's 16 channels into regs
    float wvr[2][2][3][4];
#pragma unroll
    for (int g = 0; g < 2; ++g)
#pragma unroll
        for (int ct = 0; ct < 2; ++ct) {
            int c0 = wave * 32 + ct * 16 + quad * 4;
#pragma unroll
            for (int j = 0; j < 3; ++j)
#pragma unroll
                for (int r = 0; r < 4; ++r)
                    wvr[g][ct][j][r] = wvf[g * 384 + j * 128 + c0 + r];
        }

    for (int ch = 0; ch < 4; ++ch) {
        if (ch < 3) {
#pragma unroll
            for (int j = 0; j < 4; ++j)
                st[j] = *(const u16x8*)(feats + ((size_t)(vb0 + (ch + 1) * 64 + srow[j]) << 7) + scol[j]);
        }
        f4v acc[4][2][2];
#pragma unroll
        for (int m = 0; m < 4; ++m)
#pragma unroll
            for (int g = 0; g < 2; ++g)
#pragma unroll
                for (int ct = 0; ct < 2; ++ct)
                    acc[m][g][ct] = bv[g][ct];
#pragma unroll
        for (int ks = 0; ks < 4; ++ks) {
            bf8v af[4];
#pragma unroll
            for (int m = 0; m < 4; ++m)
                af[m] = *(const bf8v*)(&As[(m * 16 + l15) * KBP + ks * 32 + quad * 8]);
#pragma unroll
            for (int m = 0; m < 4; ++m)
#pragma unroll
                for (int g = 0; g < 2; ++g)
#pragma unroll
                    for (int ct = 0; ct < 2; ++ct)
                        acc[m][g][ct] = __builtin_amdgcn_mfma_f32_16x16x32_bf16(
                            bfrag[g][ct][ks], af[m], acc[m][g][ct], 0, 0, 0);
        }
        int vbase = vb0 + ch * 64;
#pragma unroll
        for (int m = 0; m < 4; ++m) {
            int rloc = ch * 64 + m * 16 + l15;
            int vtx  = vbase + m * 16 + l15;
            float vx = vlds[rloc * 3 + 0];
            float vy = vlds[rloc * 3 + 1];
            float vz = vlds[rloc * 3 + 2];
#pragma unroll
            for (int g = 0; g < 2; ++g) {
                unsigned short* dst = g ? z : y;
#pragma unroll
                for (int ct = 0; ct < 2; ++ct) {
                    int c0 = wave * 32 + ct * 16 + quad * 4;
                    u16x4 pv;
#pragma unroll
                    for (int r = 0; r < 4; ++r) {
                        float t = acc[m][g][ct][r]
                                + vx * wvr[g][ct][0][r]
                                + vy * wvr[g][ct][1][r]
                                + vz * wvr[g][ct][2][r];
                        pv[r] = f2bf(t);
                    }
                    *(u16x4*)(&dst[(size_t)vtx * HID + c0]) = pv;
                }
            }
        }
        __syncthreads();
        if (ch < 3) {
#pragma unroll
            for (int j = 0; j < 4; ++j)
                *(u16x8*)(&As[srow[j] * KBP + scol[j]]) = st[j];
            __syncthreads();
        }
    }
}

// ---- CSR build via 2-level bucket sort ----
__global__ __launch_bounds__(256) void k_hist(const int4* __restrict__ edges4,
                                              int* __restrict__ gcount) {
    __shared__ int hist[NBKT];
    if (threadIdx.x < NBKT) hist[threadIdx.x] = 0;
    __syncthreads();
#pragma unroll
    for (int i = 0; i < 4; ++i) {
        int4 e = edges4[(size_t)blockIdx.x * 1024 + i * 256 + threadIdx.x];
        atomicAdd(&hist[e.x >> 10], 1);
        atomicAdd(&hist[e.y >> 10], 1);
        atomicAdd(&hist[e.z >> 10], 1);
        atomicAdd(&hist[e.w >> 10], 1);
    }
    __syncthreads();
    if (threadIdx.x < NBKT) atomicAdd(&gcount[threadIdx.x], hist[threadIdx.x]);
}

__global__ __launch_bounds__(256) void k_scan256(const int* __restrict__ gcount,
                                                 int* __restrict__ bbase,
                                                 int* __restrict__ bcur,
                                                 int* __restrict__ rowstart) {
    __shared__ int s[NBKT];
    int t = threadIdx.x;
    int c = gcount[t];
    s[t] = c;
    __syncthreads();
    for (int off = 1; off < NBKT; off <<= 1) {
        int v = (t >= off) ? s[t - off] : 0;
        __syncthreads();
        s[t] += v;
        __syncthreads();
    }
    bbase[t] = s[t] - c;
    bcur[t]  = s[t] - c;
    if (t == NBKT - 1) {
        bbase[NBKT] = s[t];
        rowstart[NV] = s[t];
    }
}

__global__ __launch_bounds__(256) void k_binA(const int4* __restrict__ edges4,
                                              int* __restrict__ bcur,
                                              unsigned int* __restrict__ items) {
    __shared__ int hist[NBKT];
    __shared__ int loff[NBKT];
    __shared__ int gbase[NBKT];
    __shared__ int sscan[256];
    __shared__ unsigned int staged[4096];
    __shared__ unsigned char staged_b[4096];

    if (threadIdx.x < NBKT) hist[threadIdx.x] = 0;
    __syncthreads();

    int vv[16], uu[16], rk[16];
#pragma unroll
    for (int i = 0; i < 4; ++i) {
        int4 e = edges4[(size_t)blockIdx.x * 1024 + i * 256 + threadIdx.x];
        vv[4*i+0] = e.x; uu[4*i+0] = e.y;
        vv[4*i+1] = e.y; uu[4*i+1] = e.x;
        vv[4*i+2] = e.z; uu[4*i+2] = e.w;
        vv[4*i+3] = e.w; uu[4*i+3] = e.z;
    }
#pragma unroll
    for (int i = 0; i < 16; ++i) rk[i] = atomicAdd(&hist[vv[i] >> 10], 1);
    __syncthreads();
    {
        int t = threadIdx.x;
        int c = hist[t];
        sscan[t] = c;
        __syncthreads();
        for (int off = 1; off < 256; off <<= 1) {
            int x = (t >= off) ? sscan[t - off] : 0;
            __syncthreads();
            sscan[t] += x;
            __syncthreads();
        }
        loff[t] = sscan[t] - c;
    }
    __syncthreads();
#pragma unroll
    for (int i = 0; i < 16; ++i) {
        int b = vv[i] >> 10;
        int pos = loff[b] + rk[i];
        staged[pos] = ((unsigned int)(vv[i] & 1023) << 18) | (unsigned int)uu[i];
        staged_b[pos] = (unsigned char)b;
    }
    __syncthreads();
    if (threadIdx.x < NBKT)
        gbase[threadIdx.x] = atomicAdd(&bcur[threadIdx.x], hist[threadIdx.x]);
    __syncthreads();
#pragma unroll
    for (int i = 0; i < 16; ++i) {
        int s = i * 256 + threadIdx.x;
        int b = staged_b[s];
        items[(size_t)gbase[b] + (s - loff[b])] = staged[s];
    }
}

__global__ __launch_bounds__(256) void k_binB(const unsigned int* __restrict__ items,
                                              const int* __restrict__ bbase,
                                              int* __restrict__ rowstart,
                                              int* __restrict__ adj) {
    __shared__ int cnt[1024];
    __shared__ int sscan[256];
    int b = blockIdx.x;
    int base = bbase[b];
    int size = bbase[b + 1] - base;
#pragma unroll
    for (int i = 0; i < 4; ++i) cnt[i * 256 + threadIdx.x] = 0;
    __syncthreads();
    for (int i = threadIdx.x; i < size; i += 256) {
        unsigned int it = items[(size_t)base + i];
        atomicAdd(&cnt[(it >> 18) & 1023], 1);
    }
    __syncthreads();
    {
        int j = threadIdx.x;
        int c[4], t = 0;
#pragma unroll
        for (int i = 0; i < 4; ++i) { c[i] = cnt[4 * j + i]; t += c[i]; }
        sscan[j] = t;
        __syncthreads();
        for (int off = 1; off < 256; off <<= 1) {
            int x = (j >= off) ? sscan[j - off] : 0;
            __syncthreads();
            sscan[j] += x;
            __syncthreads();
        }
        int pre = sscan[j] - t;
#pragma unroll
        for (int i = 0; i < 4; ++i) {
            cnt[4 * j + i] = pre;
            rowstart[b * 1024 + 4 * j + i] = base + pre;
            pre += c[i];
        }
    }
    __syncthreads();
    for (int i = threadIdx.x; i < size; i += 256) {
        unsigned int it = items[(size_t)base + i];
        int lv = (it >> 18) & 1023;
        int rel = atomicAdd(&cnt[lv], 1);
        // store neighbor pre-scaled to element offset into a 128-ch row
        adj[base + rel] = (int)((it & 0x3FFFFu) << 7);
    }
}

// relu(y[v] + sum_{u in N(v)} z[u]); 16 lanes/vertex.
// Streaming accesses (ybf read, acc/out writes) are NON-TEMPORAL so the
// randomly-gathered zbf (64 MB) stays L3-resident.
template <bool LAST>
__global__ __launch_bounds__(256) void k_gather(const int* __restrict__ rowstart,
                                                const int* __restrict__ adj,
                                                const unsigned short* __restrict__ zbf,
                                                const unsigned short* __restrict__ ybf,
                                                unsigned short* __restrict__ featdst,
                                                float* __restrict__ accdst,
                                                const float* __restrict__ verts,
                                                const float* __restrict__ ow,
                                                const float* __restrict__ ob,
                                                float* __restrict__ outp) {
    __shared__ float owl[DIN * 3];
    if (LAST) {
        for (int idx = threadIdx.x; idx < DIN * 3; idx += 256) owl[idx] = ow[idx];
        __syncthreads();
    }
    int cq = threadIdx.x & 15;
    int co = 8 * cq;
    int v  = blockIdx.x * 16 + (threadIdx.x >> 4);
    int start = rowstart[v], end = rowstart[v + 1];
    u16x8 yy = __builtin_nontemporal_load((const u16x8*)(ybf + ((unsigned)v << 7) + co));
    float a0[8], a1[8];
#pragma unroll
    for (int i = 0; i < 8; ++i) { a0[i] = bf2f(yy[i]); a1[i] = 0.f; }
    int n = start;
    for (; n + 4 <= end; n += 4) {
        int u0 = adj[n + 0], u1 = adj[n + 1];
        int u2 = adj[n + 2], u3 = adj[n + 3];
        u16x8 z0 = *(const u16x8*)(zbf + (unsigned)(u0 + co));
        u16x8 z1 = *(const u16x8*)(zbf + (unsigned)(u1 + co));
        u16x8 z2 = *(const u16x8*)(zbf + (unsigned)(u2 + co));
        u16x8 z3 = *(const u16x8*)(zbf + (unsigned)(u3 + co));
#pragma unroll
        for (int i = 0; i < 8; ++i) a0[i] += bf2f(z0[i]) + bf2f(z1[i]);
#pragma unroll
        for (int i = 0; i < 8; ++i) a1[i] += bf2f(z2[i]) + bf2f(z3[i]);
    }
    if (n + 2 <= end) {
        int u0 = adj[n + 0], u1 = adj[n + 1];
        u16x8 z0 = *(const u16x8*)(zbf + (unsigned)(u0 + co));
        u16x8 z1 = *(const u16x8*)(zbf + (unsigned)(u1 + co));
#pragma unroll
        for (int i = 0; i < 8; ++i) a0[i] += bf2f(z0[i]) + bf2f(z1[i]);
        n += 2;
    }
    if (n < end) {
        int u = adj[n];
        u16x8 zz = *(const u16x8*)(zbf + (unsigned)(u + co));
#pragma unroll
        for (int i = 0; i < 8; ++i) a1[i] += bf2f(zz[i]);
    }
    float a[8];
#pragma unroll
    for (int i = 0; i < 8; ++i) a[i] = fmaxf(a0[i] + a1[i], 0.f);
    if (LAST) {
        f4v lo = {a[0], a[1], a[2], a[3]};
        f4v hi = {a[4], a[5], a[6], a[7]};
        float* dst = accdst + ((size_t)v << 7) + co;
        __builtin_nontemporal_store(lo, (f4v*)(dst + 0));
        __builtin_nontemporal_store(hi, (f4v*)(dst + 4));
        float d0 = 0.f, d1 = 0.f, d2 = 0.f;
#pragma unroll
        for (int i = 0; i < 8; ++i) {
            int k = co + i;
            d0 += a[i] * owl[k * 3 + 0];
            d1 += a[i] * owl[k * 3 + 1];
            d2 += a[i] * owl[k * 3 + 2];
        }
#pragma unroll
        for (int off = 8; off > 0; off >>= 1) {
            d0 += __shfl_down(d0, off, 16);
            d1 += __shfl_down(d1, off, 16);
            d2 += __shfl_down(d2, off, 16);
        }
        if (cq == 0) {
            float vx = verts[(size_t)v * 3 + 0];
            float vy = verts[(size_t)v * 3 + 1];
            float vz = verts[(size_t)v * 3 + 2];
            d0 += vx * owl[128*3+0] + vy * owl[129*3+0] + vz * owl[130*3+0] + ob[0];
            d1 += vx * owl[128*3+1] + vy * owl[129*3+1] + vz * owl[130*3+1] + ob[1];
            d2 += vx * owl[128*3+2] + vy * owl[129*3+2] + vz * owl[130*3+2] + ob[2];
            outp[(size_t)v * 3 + 0] = vx + tanhf(d0);
            outp[(size_t)v * 3 + 1] = vy + tanhf(d1);
            outp[(size_t)v * 3 + 2] = vz + tanhf(d2);
        }
    } else {
        u16x8 o;
#pragma unroll
        for (int i = 0; i < 8; ++i) o[i] = f2bf(a[i]);
        *(u16x8*)(featdst + ((size_t)v << 7) + co) = o;
    }
}

extern "C" void kernel_launch(void* const* d_in, const int* in_sizes, int n_in,
                              void* d_out, int out_size, void* d_ws, size_t ws_size,
                              hipStream_t stream) {
    const float* x     = (const float*)d_in[0];
    const float* verts = (const float*)d_in[1];
    const int*   edges = (const int*)d_in[2];
    const float* bw    = (const float*)d_in[3];
    const float* bb    = (const float*)d_in[4];
    const float* w0    = (const float*)d_in[5];
    const float* b0    = (const float*)d_in[6];
    const float* w1    = (const float*)d_in[7];
    const float* b1    = (const float*)d_in[8];
    const float* ow    = (const float*)d_in[9];
    const float* ob    = (const float*)d_in[10];
    float* out = (float*)d_out;

    char* w = (char*)d_ws;
    float* P              = (float*)w;          w += (size_t)NPIX * HID * 4;
    unsigned short* feats = (unsigned short*)w; w += (size_t)NV * KB * 2;
    unsigned short* zbf   = (unsigned short*)w; w += (size_t)NV * HID * 2;
    unsigned short* ybf   = (unsigned short*)w; w += (size_t)NV * HID * 2;
    unsigned short* Wt    = (unsigned short*)w; w += (size_t)6 * 128 * KB * 2;
    int* adj              = (int*)w;            w += (size_t)2 * NE * 4;
    unsigned int* items   = (unsigned int*)w;   w += (size_t)2 * NE * 4;
    int* rowstart         = (int*)w;            w += (size_t)(NV + 1) * 4;
    int* gcount           = (int*)w;            w += 512 * 4;
    int* bbase            = (int*)w;            w += 512 * 4;
    int* bcur             = (int*)w;            w += 512 * 4;
    float* acc            = out + (size_t)3 * NV;

    hipMemsetAsync(gcount, 0, NBKT * 4, stream);
    k_hist<<<NE / 2048, 256, 0, stream>>>((const int4*)edges, gcount);
    k_scan256<<<1, 256, 0, stream>>>(gcount, bbase, bcur, rowstart);
    k_binA<<<NE / 2048, 256, 0, stream>>>((const int4*)edges, bcur, items);
    k_binB<<<NBKT, 256, 0, stream>>>(items, bbase, rowstart, adj);

    k_prepw<<<3, 256, 0, stream>>>(w0, w1, Wt);
    k_project<<<NPIX / 8, 256, 0, stream>>>(x, bw, P);
    k_sample<<<NV / 16, 256, 0, stream>>>(P, verts, bb, feats);

    for (int i = 0; i < 3; ++i) {
        const unsigned short* Wt0 = Wt + (size_t)(2 * i + 0) * 128 * KB;
        const unsigned short* Wt1 = Wt + (size_t)(2 * i + 1) * 128 * KB;
        const float* wv0 = w0 + (size_t)i * DIN * HID + (size_t)128 * HID;
        const float* wv1 = w1 + (size_t)i * DIN * HID + (size_t)128 * HID;
        k_gemm2<<<NV / 256, 256, 0, stream>>>(feats, Wt0, Wt1, wv0, wv1,
                                              b0 + (size_t)i * HID, b1 + (size_t)i * HID,
                                              verts, ybf, zbf);
        if (i < 2) k_gather<false><<<NV / 16, 256, 0, stream>>>(rowstart, adj, zbf, ybf,
                                                                feats, nullptr, verts,
                                                                nullptr, nullptr, nullptr);
        else       k_gather<true ><<<NV / 16, 256, 0, stream>>>(rowstart, adj, zbf, ybf,
                                                                nullptr, acc, verts,
                                                                ow, ob, out);
    }
}